// Round 9
// baseline (181.935 us; speedup 1.0000x reference)
//
#include <hip/hip_runtime.h>
#include <hip/hip_bf16.h>
#include <math.h>

#define NSRC 50000
#define NTGT 50000
#define NTOT 100000
#define NEDGE 800000
#define DIM 128
#define WPAD 136        // Wt LDS row pitch (ushorts): 2-way bank alias = free
#define HPITCH 136      // Hs row pitch (ushorts): b64 epilogue writes 2-way max
#define CHUNKS_PER_BLK 2
#define GEMM_GRID 782   // ceil(1563 / 2)

#define NBUCK 196       // coarse buckets of 256 targets (49999>>8 = 195)
#define PBLK 98         // partition blocks
#define EPB 8192        // edges per partition block (98*8192 >= 800000)
#define BCAP 6144       // max edges per bucket (mean 4096, +32 sigma)

typedef __attribute__((ext_vector_type(8))) short short8;
typedef __attribute__((ext_vector_type(4))) float float4v;

union U8 { short8 s; uint4 u; };

__device__ __forceinline__ unsigned short f2bf(float f) {
    unsigned u = __float_as_uint(f);
    unsigned r = (u + 0x7FFFu + ((u >> 16) & 1u)) >> 16;  // RNE
    return (unsigned short)r;
}
__device__ __forceinline__ float bf2f(unsigned us) {
    return __uint_as_float(us << 16);
}
// packed RNE f32x2 -> bf16x2 (v_cvt_pk_bf16_f32)
__device__ __forceinline__ unsigned pkbf(float lo, float hi) {
    __hip_bfloat162 b = __float22bfloat162_rn(make_float2(lo, hi));
    return *(unsigned*)&b;
}

// ---------------- prep: W -> Wt (bf16, transposed) + zero bcnt ------------
__global__ void k_prep(const float* __restrict__ W, unsigned short* __restrict__ Wt,
                       int* __restrict__ bcnt) {
    int i = blockIdx.x * blockDim.x + threadIdx.x;
    if (i < NBUCK) bcnt[i] = 0;
    if (i < DIM * DIM) {
        int k = i >> 7, n = i & 127;
        Wt[n * DIM + k] = f2bf(W[i]);
    }
}

// ---------------- fused count + run-reserve + partition ----------------
// packed entry: row (16 bits) | c_local (bits 16..23)
__global__ __launch_bounds__(1024) void k_part2(const int* __restrict__ row,
                                                const int* __restrict__ col,
                                                int* __restrict__ bcnt,
                                                unsigned* __restrict__ part) {
    __shared__ int hist[NBUCK], runbase[NBUCK], cur[NBUCK];
    int tid = threadIdx.x;
    if (tid < NBUCK) hist[tid] = 0;
    __syncthreads();
    int e0 = blockIdx.x * EPB;
    int eend = (e0 + EPB < NEDGE) ? e0 + EPB : NEDGE;
    for (int e = e0 + tid; e < eend; e += 1024)
        atomicAdd(&hist[col[e] >> 8], 1);
    __syncthreads();
    if (tid < NBUCK) {
        runbase[tid] = atomicAdd(&bcnt[tid], hist[tid]);  // reserve run
        cur[tid] = 0;
    }
    __syncthreads();
    for (int e = e0 + tid; e < eend; e += 1024) {
        int c = col[e];
        int q = c >> 8;
        int pos = runbase[q] + atomicAdd(&cur[q], 1);
        part[q * BCAP + pos] = (unsigned)row[e] | ((unsigned)(c & 255) << 16);
    }
}

// ---------------- per-bucket local sort -> csr (ushort) + tstart/tcnt -----
__global__ __launch_bounds__(1024) void k_bucket(const int* __restrict__ bcnt,
                                                 const unsigned* __restrict__ part,
                                                 unsigned short* __restrict__ csr,
                                                 int* __restrict__ tstart,
                                                 int* __restrict__ tcnt) {
    __shared__ unsigned ebuf[BCAP];
    __shared__ unsigned short srt[BCAP];
    __shared__ int hist[256], bufA[256], bufB[256], cur[256];

    int q = blockIdx.x, tid = threadIdx.x;
    int n = bcnt[q];
    int base = q * BCAP;

    if (tid < 256) hist[tid] = 0;
    __syncthreads();
    for (int i = tid; i < n; i += 1024) {
        unsigned p = part[base + i];
        ebuf[i] = p;
        atomicAdd(&hist[p >> 16], 1);
    }
    __syncthreads();

    // exclusive scan of hist[256] (first 256 threads, double-buffered)
    if (tid < 256) bufA[tid] = hist[tid];
    int* src = bufA; int* dst = bufB;
    for (int d = 1; d < 256; d <<= 1) {
        __syncthreads();
        if (tid < 256) dst[tid] = src[tid] + ((tid >= d) ? src[tid - d] : 0);
        int* t = src; src = dst; dst = t;
    }
    __syncthreads();
    if (tid < 256) {
        int excl = src[tid] - hist[tid];
        cur[tid] = excl;
        int c = q * 256 + tid;
        if (c < NTGT) {
            tstart[c] = base + excl;
            tcnt[c] = hist[tid];
        }
    }
    __syncthreads();

    for (int i = tid; i < n; i += 1024) {
        unsigned p = ebuf[i];
        int pos = atomicAdd(&cur[p >> 16], 1);
        srt[pos] = (unsigned short)(p & 0xffffu);
    }
    __syncthreads();
    // coalesced writeout, 2 ushorts per store (base is 4B-aligned: BCAP even)
    int m = (n + 1) >> 1;
    unsigned* dst32 = (unsigned*)(csr + base);
    for (int i = tid; i < m; i += 1024) dst32[i] = ((unsigned*)srt)[i];
}

// ---------------- h = x @ W via bf16 MFMA (operand-swapped) ---------------
// mfma(A=W^T frag, B=x frag): C row=feature, col=node -> each lane holds 4
// consecutive features of one node -> packed b64 epilogue stores.
__global__ __launch_bounds__(256) void k_gemm(const float* __restrict__ xsrc,
                                              const float* __restrict__ xtgt,
                                              const unsigned short* __restrict__ Wt,
                                              unsigned short* __restrict__ h,
                                              float* __restrict__ out) {
    __shared__ unsigned short Bs[128 * WPAD];    // 34 KB: [n][k] bf16, padded
    __shared__ unsigned short Hs[64 * HPITCH];   // 17 KB epilogue staging

    const int tid = threadIdx.x;

    for (int idx = tid; idx < 2048; idx += 256) {
        int n = idx >> 4, c8 = idx & 15;
        uint4 v = *(const uint4*)(Wt + n * DIM + c8 * 8);
        *(uint4*)&Bs[n * WPAD + c8 * 8] = v;
    }
    __syncthreads();

    const int wave = tid >> 6, lane = tid & 63;
    const int nl = lane & 15, quad = lane >> 4;

    for (int ch = 0; ch < CHUNKS_PER_BLK; ++ch) {
        const int base = (blockIdx.x * CHUNKS_PER_BLK + ch) * 64;
        if (base >= NTOT) break;  // block-uniform

        int m = base + wave * 16 + nl;
        int mc = (m < NTOT) ? m : (NTOT - 1);
        const float* xrow = (mc < NSRC) ? (xsrc + (size_t)mc * DIM)
                                        : (xtgt + (size_t)(mc - NSRC) * DIM);

        float4v acc[8];
#pragma unroll
        for (int t = 0; t < 8; ++t) acc[t] = (float4v){0.f, 0.f, 0.f, 0.f};

#pragma unroll
        for (int s = 0; s < 4; ++s) {
            int k0 = s * 32 + quad * 8;
            float4 a0 = *(const float4*)(xrow + k0);
            float4 a1 = *(const float4*)(xrow + k0 + 4);
            U8 af;
            af.u.x = pkbf(a0.x, a0.y);
            af.u.y = pkbf(a0.z, a0.w);
            af.u.z = pkbf(a1.x, a1.y);
            af.u.w = pkbf(a1.z, a1.w);
#pragma unroll
            for (int t = 0; t < 8; ++t) {
                short8 bf = *(const short8*)&Bs[(t * 16 + nl) * WPAD + k0];
                // A = W^T tile (features as M), B = x tile (nodes as N)
                acc[t] = __builtin_amdgcn_mfma_f32_16x16x32_bf16(bf, af.s, acc[t], 0, 0, 0);
            }
        }

        if (ch) __syncthreads();  // Hs readout of prev chunk complete
        // C layout (swapped): col=node=nl, row=feature=quad*4+r (+t*16)
        // lane stores 4 consecutive features of node nl -> one b64 per tile
#pragma unroll
        for (int t = 0; t < 8; ++t) {
            uint2 p;
            p.x = pkbf(acc[t][0], acc[t][1]);
            p.y = pkbf(acc[t][2], acc[t][3]);
            *(uint2*)&Hs[(wave * 16 + nl) * HPITCH + t * 16 + quad * 4] = p;
        }
        __syncthreads();

        // coalesced readout: 4 threads per row, each 32 cols (4 uint4)
        int r_ = tid >> 2, cq = (tid & 3) * 32;
        int g = base + r_;
        if (g < NTOT) {
            const unsigned short* hsrow = &Hs[r_ * HPITCH + cq];
            unsigned short* hrow = h + (size_t)g * DIM + cq;
            float* orow = out + (size_t)g * DIM + cq;
            bool isrc = (g < NSRC);
#pragma unroll
            for (int jj = 0; jj < 4; ++jj) {
                uint4 v = *(const uint4*)(hsrow + jj * 8);
                *(uint4*)(hrow + jj * 8) = v;
                if (isrc) {  // source nodes: deg=1 -> out = relu(h)
                    float4 o0, o1;
                    o0.x = fmaxf(bf2f(v.x & 0xffff), 0.f);
                    o0.y = fmaxf(bf2f(v.x >> 16), 0.f);
                    o0.z = fmaxf(bf2f(v.y & 0xffff), 0.f);
                    o0.w = fmaxf(bf2f(v.y >> 16), 0.f);
                    o1.x = fmaxf(bf2f(v.z & 0xffff), 0.f);
                    o1.y = fmaxf(bf2f(v.z >> 16), 0.f);
                    o1.z = fmaxf(bf2f(v.w & 0xffff), 0.f);
                    o1.w = fmaxf(bf2f(v.w >> 16), 0.f);
                    *(float4*)(orow + jj * 8) = o0;
                    *(float4*)(orow + jj * 8 + 4) = o1;
                }
            }
        }
        if (ch + 1 < CHUNKS_PER_BLK) __syncthreads();
    }
}

// ---------------- per-target gather-reduce (bf16 h, 4 edges/iter) ---------
// one wave per target; quarter-wave (16 lanes) per edge, uint4 (8 bf16)/lane
__global__ __launch_bounds__(256) void k_agg(const int* __restrict__ tstart,
                                             const int* __restrict__ tcnt,
                                             const unsigned short* __restrict__ csr,
                                             const unsigned short* __restrict__ h,
                                             float* __restrict__ out) {
    int w = threadIdx.x >> 6;
    int lane = threadIdx.x & 63;
    int c = blockIdx.x * 4 + w;
    if (c >= NTGT) return;

    int n = tcnt[c];
    int s0 = tstart[c];
    int q = lane >> 4;      // quarter: which edge of the group of 4
    int ql = lane & 15;     // covers cols 8*ql .. 8*ql+7

    float acc[8];
#pragma unroll
    for (int i = 0; i < 8; ++i) acc[i] = 0.f;

    int j = 0;
    while (j < n) {
        int nb = (n - j < 64) ? (n - j) : 64;
        int v = (lane < nb) ? (int)csr[s0 + j + lane] : 0;
        int n4 = nb & ~3;
        int kk = 0;
#pragma unroll 4
        for (; kk < n4; kk += 4) {
            int r = __shfl(v, kk + q, 64);
            uint4 d = *(const uint4*)(h + (size_t)r * DIM + ql * 8);
            acc[0] += bf2f(d.x & 0xffff); acc[1] += bf2f(d.x >> 16);
            acc[2] += bf2f(d.y & 0xffff); acc[3] += bf2f(d.y >> 16);
            acc[4] += bf2f(d.z & 0xffff); acc[5] += bf2f(d.z >> 16);
            acc[6] += bf2f(d.w & 0xffff); acc[7] += bf2f(d.w >> 16);
        }
        int rem = nb - kk;  // 0..3, wave-uniform
        if (rem) {
            // shfl executed by ALL lanes (divergent-source bpermute is UB)
            int qq = (q < rem) ? q : 0;
            int r = __shfl(v, kk + qq, 64);
            if (q < rem) {
                uint4 d = *(const uint4*)(h + (size_t)r * DIM + ql * 8);
                acc[0] += bf2f(d.x & 0xffff); acc[1] += bf2f(d.x >> 16);
                acc[2] += bf2f(d.y & 0xffff); acc[3] += bf2f(d.y >> 16);
                acc[4] += bf2f(d.z & 0xffff); acc[5] += bf2f(d.z >> 16);
                acc[6] += bf2f(d.w & 0xffff); acc[7] += bf2f(d.w >> 16);
            }
        }
        j += nb;
    }

    // combine quarters: butterfly over lane bits 4,5
#pragma unroll
    for (int i = 0; i < 8; ++i) {
        acc[i] += __shfl_xor(acc[i], 16, 64);
        acc[i] += __shfl_xor(acc[i], 32, 64);
    }

    if (q == 0) {
        float di = rsqrtf(1.0f + (float)n);
        float dd = di * di;
        uint4 dh = *(const uint4*)(h + (size_t)(NSRC + c) * DIM + ql * 8);
        float4 o0, o1;
        o0.x = fmaxf(di * acc[0] + dd * bf2f(dh.x & 0xffff), 0.f);
        o0.y = fmaxf(di * acc[1] + dd * bf2f(dh.x >> 16), 0.f);
        o0.z = fmaxf(di * acc[2] + dd * bf2f(dh.y & 0xffff), 0.f);
        o0.w = fmaxf(di * acc[3] + dd * bf2f(dh.y >> 16), 0.f);
        o1.x = fmaxf(di * acc[4] + dd * bf2f(dh.z & 0xffff), 0.f);
        o1.y = fmaxf(di * acc[5] + dd * bf2f(dh.z >> 16), 0.f);
        o1.z = fmaxf(di * acc[6] + dd * bf2f(dh.w & 0xffff), 0.f);
        o1.w = fmaxf(di * acc[7] + dd * bf2f(dh.w >> 16), 0.f);
        float* op = out + (size_t)(NSRC + c) * DIM + ql * 8;
        *(float4*)op = o0;
        *(float4*)(op + 4) = o1;
    }
}

extern "C" void kernel_launch(void* const* d_in, const int* in_sizes, int n_in,
                              void* d_out, int out_size, void* d_ws, size_t ws_size,
                              hipStream_t stream) {
    const int* ei     = (const int*)d_in[0];    // [2, E] int32
    const float* xsrc = (const float*)d_in[1];  // [NSRC, 128]
    const float* xtgt = (const float*)d_in[2];  // [NTGT, 128]
    const float* W    = (const float*)d_in[3];  // [128, 128]
    float* out = (float*)d_out;                 // [NTOT, 128]

    const int* row = ei;
    const int* col = ei + NEDGE;

    char* ws = (char*)d_ws;
    unsigned short* h  = (unsigned short*)ws;  ws += (size_t)NTOT * DIM * 2;   // 25.6 MB
    unsigned short* Wt = (unsigned short*)ws;  ws += DIM * DIM * 2;            // 32 KB
    unsigned* part = (unsigned*)ws;            ws += (size_t)NBUCK * BCAP * 4; // 4.8 MB
    unsigned short* csr = (unsigned short*)ws; ws += (size_t)NBUCK * BCAP * 2; // 2.4 MB
    int* bcnt   = (int*)ws;                    ws += NBUCK * 4;
    int* tstart = (int*)ws;                    ws += NTGT * 4;
    int* tcnt   = (int*)ws;                    ws += NTGT * 4;

    k_prep<<<(DIM * DIM + 255) / 256, 256, 0, stream>>>(W, Wt, bcnt);
    k_part2<<<PBLK, 1024, 0, stream>>>(row, col, bcnt, part);
    k_bucket<<<NBUCK, 1024, 0, stream>>>(bcnt, part, csr, tstart, tcnt);
    k_gemm<<<GEMM_GRID, 256, 0, stream>>>(xsrc, xtgt, Wt, h, out);
    k_agg<<<(NTGT + 3) / 4, 256, 0, stream>>>(tstart, tcnt, csr, h, out);
}

// Round 10
// 174.663 us; speedup vs baseline: 1.0416x; 1.0416x over previous
//
#include <hip/hip_runtime.h>
#include <hip/hip_bf16.h>
#include <math.h>

#define NSRC 50000
#define NTGT 50000
#define NTOT 100000
#define NEDGE 800000
#define DIM 128
#define WPAD 136        // Bs LDS row pitch (ushorts): 2-way bank alias = free
#define GEMM_GRID 782   // ceil(100000 / 128)

#define NBUCK 196       // coarse buckets of 256 targets (49999>>8 = 195)
#define PBLK 98         // partition blocks
#define EPB 8192        // edges per partition block (98*8192 >= 800000)
#define BCAP 6144       // max edges per bucket (mean 4096, +32 sigma)

typedef __attribute__((ext_vector_type(8))) short short8;
typedef __attribute__((ext_vector_type(4))) float float4v;

union U8 { short8 s; uint4 u; };

__device__ __forceinline__ unsigned short f2bf(float f) {
    unsigned u = __float_as_uint(f);
    unsigned r = (u + 0x7FFFu + ((u >> 16) & 1u)) >> 16;  // RNE
    return (unsigned short)r;
}
__device__ __forceinline__ float bf2f(unsigned us) {
    return __uint_as_float(us << 16);
}
// packed RNE f32x2 -> bf16x2 (v_cvt_pk_bf16_f32)
__device__ __forceinline__ unsigned pkbf(float lo, float hi) {
    __hip_bfloat162 b = __float22bfloat162_rn(make_float2(lo, hi));
    return *(unsigned*)&b;
}

// ---------------- prep: W -> Wt (bf16, transposed) + zero bcnt ------------
__global__ void k_prep(const float* __restrict__ W, unsigned short* __restrict__ Wt,
                       int* __restrict__ bcnt) {
    int i = blockIdx.x * blockDim.x + threadIdx.x;
    if (i < NBUCK) bcnt[i] = 0;
    if (i < DIM * DIM) {
        int k = i >> 7, n = i & 127;
        Wt[n * DIM + k] = f2bf(W[i]);
    }
}

// ---------------- fused count + run-reserve + partition ----------------
// packed entry: row (16 bits) | c_local (bits 16..23)
__global__ __launch_bounds__(1024) void k_part2(const int* __restrict__ row,
                                                const int* __restrict__ col,
                                                int* __restrict__ bcnt,
                                                unsigned* __restrict__ part) {
    __shared__ int hist[NBUCK], runbase[NBUCK], cur[NBUCK];
    int tid = threadIdx.x;
    if (tid < NBUCK) hist[tid] = 0;
    __syncthreads();
    int e0 = blockIdx.x * EPB;
    int eend = (e0 + EPB < NEDGE) ? e0 + EPB : NEDGE;
    for (int e = e0 + tid; e < eend; e += 1024)
        atomicAdd(&hist[col[e] >> 8], 1);
    __syncthreads();
    if (tid < NBUCK) {
        runbase[tid] = atomicAdd(&bcnt[tid], hist[tid]);  // reserve run
        cur[tid] = 0;
    }
    __syncthreads();
    for (int e = e0 + tid; e < eend; e += 1024) {
        int c = col[e];
        int q = c >> 8;
        int pos = runbase[q] + atomicAdd(&cur[q], 1);
        part[q * BCAP + pos] = (unsigned)row[e] | ((unsigned)(c & 255) << 16);
    }
}

// ---------------- per-bucket local sort -> csr (ushort) + tstart/tcnt -----
__global__ __launch_bounds__(1024) void k_bucket(const int* __restrict__ bcnt,
                                                 const unsigned* __restrict__ part,
                                                 unsigned short* __restrict__ csr,
                                                 int* __restrict__ tstart,
                                                 int* __restrict__ tcnt) {
    __shared__ unsigned ebuf[BCAP];
    __shared__ unsigned short srt[BCAP];
    __shared__ int hist[256], bufA[256], bufB[256], cur[256];

    int q = blockIdx.x, tid = threadIdx.x;
    int n = bcnt[q];
    int base = q * BCAP;

    if (tid < 256) hist[tid] = 0;
    __syncthreads();
    for (int i = tid; i < n; i += 1024) {
        unsigned p = part[base + i];
        ebuf[i] = p;
        atomicAdd(&hist[p >> 16], 1);
    }
    __syncthreads();

    // exclusive scan of hist[256] (first 256 threads, double-buffered)
    if (tid < 256) bufA[tid] = hist[tid];
    int* src = bufA; int* dst = bufB;
    for (int d = 1; d < 256; d <<= 1) {
        __syncthreads();
        if (tid < 256) dst[tid] = src[tid] + ((tid >= d) ? src[tid - d] : 0);
        int* t = src; src = dst; dst = t;
    }
    __syncthreads();
    if (tid < 256) {
        int excl = src[tid] - hist[tid];
        cur[tid] = excl;
        int c = q * 256 + tid;
        if (c < NTGT) {
            tstart[c] = base + excl;
            tcnt[c] = hist[tid];
        }
    }
    __syncthreads();

    for (int i = tid; i < n; i += 1024) {
        unsigned p = ebuf[i];
        int pos = atomicAdd(&cur[p >> 16], 1);
        srt[pos] = (unsigned short)(p & 0xffffu);
    }
    __syncthreads();
    // coalesced writeout, 2 ushorts per store (base is 4B-aligned: BCAP even)
    int m = (n + 1) >> 1;
    unsigned* dst32 = (unsigned*)(csr + base);
    for (int i = tid; i < m; i += 1024) dst32[i] = ((unsigned*)srt)[i];
}

// ---------------- h = x @ W via bf16 MFMA (operand-swapped, no Hs) --------
// mfma(A=W^T frag, B=x frag): C row=feature, col=node -> each lane holds 4
// consecutive features of one node -> direct uint2 global stores, no LDS
// epilogue staging. Both chunks' A-loads prefetched upfront (16 dwordx4).
__global__ __launch_bounds__(256) void k_gemm(const float* __restrict__ xsrc,
                                              const float* __restrict__ xtgt,
                                              const unsigned short* __restrict__ Wt,
                                              unsigned short* __restrict__ h,
                                              float* __restrict__ out) {
    __shared__ unsigned short Bs[128 * WPAD];  // 34 KB only -> 4 blocks/CU

    const int tid = threadIdx.x;
    for (int idx = tid; idx < 2048; idx += 256) {
        int n = idx >> 4, c8 = idx & 15;
        *(uint4*)&Bs[n * WPAD + c8 * 8] = *(const uint4*)(Wt + n * DIM + c8 * 8);
    }

    const int wave = tid >> 6, lane = tid & 63;
    const int nl = lane & 15, quad = lane >> 4;

    // prefetch both chunks' x fragments (issued before the Bs barrier)
    float4 a[2][8];
    int g[2];
#pragma unroll
    for (int ch = 0; ch < 2; ++ch) {
        int m = blockIdx.x * 128 + ch * 64 + wave * 16 + nl;
        g[ch] = m;
        int mc = (m < NTOT) ? m : (NTOT - 1);  // clamp tail loads
        const float* xrow = (mc < NSRC) ? (xsrc + (size_t)mc * DIM)
                                        : (xtgt + (size_t)(mc - NSRC) * DIM);
#pragma unroll
        for (int s = 0; s < 4; ++s) {
            a[ch][2 * s]     = *(const float4*)(xrow + s * 32 + quad * 8);
            a[ch][2 * s + 1] = *(const float4*)(xrow + s * 32 + quad * 8 + 4);
        }
    }
    __syncthreads();  // Bs ready

#pragma unroll
    for (int ch = 0; ch < 2; ++ch) {
        float4v acc[8];
#pragma unroll
        for (int t = 0; t < 8; ++t) acc[t] = (float4v){0.f, 0.f, 0.f, 0.f};

#pragma unroll
        for (int s = 0; s < 4; ++s) {
            U8 af;
            af.u.x = pkbf(a[ch][2 * s].x, a[ch][2 * s].y);
            af.u.y = pkbf(a[ch][2 * s].z, a[ch][2 * s].w);
            af.u.z = pkbf(a[ch][2 * s + 1].x, a[ch][2 * s + 1].y);
            af.u.w = pkbf(a[ch][2 * s + 1].z, a[ch][2 * s + 1].w);
#pragma unroll
            for (int t = 0; t < 8; ++t) {
                short8 bf = *(const short8*)&Bs[(t * 16 + nl) * WPAD + s * 32 + quad * 8];
                // A = W^T tile (features as M), B = x tile (nodes as N)
                acc[t] = __builtin_amdgcn_mfma_f32_16x16x32_bf16(bf, af.s, acc[t], 0, 0, 0);
            }
        }

        int node = g[ch];
        if (node < NTOT) {
            // lane owns node `node`, features t*16 + quad*4 .. +3
            unsigned short* hp = h + (size_t)node * DIM + quad * 4;
            float* op = out + (size_t)node * DIM + quad * 4;
            bool isrc = (node < NSRC);
#pragma unroll
            for (int t = 0; t < 8; ++t) {
                uint2 p;
                p.x = pkbf(acc[t][0], acc[t][1]);
                p.y = pkbf(acc[t][2], acc[t][3]);
                *(uint2*)(hp + t * 16) = p;
                if (isrc) {  // source nodes: deg=1 -> out = relu(h), fp32 acc
                    float4 o;
                    o.x = fmaxf(acc[t][0], 0.f);
                    o.y = fmaxf(acc[t][1], 0.f);
                    o.z = fmaxf(acc[t][2], 0.f);
                    o.w = fmaxf(acc[t][3], 0.f);
                    *(float4*)(op + t * 16) = o;
                }
            }
        }
    }
}

// ---------------- per-target gather-reduce (bf16 h, 4 edges/iter) ---------
// one wave per target; quarter-wave (16 lanes) per edge, uint4 (8 bf16)/lane
__global__ __launch_bounds__(256) void k_agg(const int* __restrict__ tstart,
                                             const int* __restrict__ tcnt,
                                             const unsigned short* __restrict__ csr,
                                             const unsigned short* __restrict__ h,
                                             float* __restrict__ out) {
    int w = threadIdx.x >> 6;
    int lane = threadIdx.x & 63;
    int c = blockIdx.x * 4 + w;
    if (c >= NTGT) return;

    int n = tcnt[c];
    int s0 = tstart[c];
    int q = lane >> 4;      // quarter: which edge of the group of 4
    int ql = lane & 15;     // covers cols 8*ql .. 8*ql+7

    float acc[8];
#pragma unroll
    for (int i = 0; i < 8; ++i) acc[i] = 0.f;

    int j = 0;
    while (j < n) {
        int nb = (n - j < 64) ? (n - j) : 64;
        int v = (lane < nb) ? (int)csr[s0 + j + lane] : 0;
        int n4 = nb & ~3;
        int kk = 0;
#pragma unroll 4
        for (; kk < n4; kk += 4) {
            int r = __shfl(v, kk + q, 64);
            uint4 d = *(const uint4*)(h + (size_t)r * DIM + ql * 8);
            acc[0] += bf2f(d.x & 0xffff); acc[1] += bf2f(d.x >> 16);
            acc[2] += bf2f(d.y & 0xffff); acc[3] += bf2f(d.y >> 16);
            acc[4] += bf2f(d.z & 0xffff); acc[5] += bf2f(d.z >> 16);
            acc[6] += bf2f(d.w & 0xffff); acc[7] += bf2f(d.w >> 16);
        }
        int rem = nb - kk;  // 0..3, wave-uniform
        if (rem) {
            // shfl executed by ALL lanes (divergent-source bpermute is UB)
            int qq = (q < rem) ? q : 0;
            int r = __shfl(v, kk + qq, 64);
            if (q < rem) {
                uint4 d = *(const uint4*)(h + (size_t)r * DIM + ql * 8);
                acc[0] += bf2f(d.x & 0xffff); acc[1] += bf2f(d.x >> 16);
                acc[2] += bf2f(d.y & 0xffff); acc[3] += bf2f(d.y >> 16);
                acc[4] += bf2f(d.z & 0xffff); acc[5] += bf2f(d.z >> 16);
                acc[6] += bf2f(d.w & 0xffff); acc[7] += bf2f(d.w >> 16);
            }
        }
        j += nb;
    }

    // combine quarters: butterfly over lane bits 4,5
#pragma unroll
    for (int i = 0; i < 8; ++i) {
        acc[i] += __shfl_xor(acc[i], 16, 64);
        acc[i] += __shfl_xor(acc[i], 32, 64);
    }

    if (q == 0) {
        float di = rsqrtf(1.0f + (float)n);
        float dd = di * di;
        uint4 dh = *(const uint4*)(h + (size_t)(NSRC + c) * DIM + ql * 8);
        float4 o0, o1;
        o0.x = fmaxf(di * acc[0] + dd * bf2f(dh.x & 0xffff), 0.f);
        o0.y = fmaxf(di * acc[1] + dd * bf2f(dh.x >> 16), 0.f);
        o0.z = fmaxf(di * acc[2] + dd * bf2f(dh.y & 0xffff), 0.f);
        o0.w = fmaxf(di * acc[3] + dd * bf2f(dh.y >> 16), 0.f);
        o1.x = fmaxf(di * acc[4] + dd * bf2f(dh.z & 0xffff), 0.f);
        o1.y = fmaxf(di * acc[5] + dd * bf2f(dh.z >> 16), 0.f);
        o1.z = fmaxf(di * acc[6] + dd * bf2f(dh.w & 0xffff), 0.f);
        o1.w = fmaxf(di * acc[7] + dd * bf2f(dh.w >> 16), 0.f);
        float* op = out + (size_t)(NSRC + c) * DIM + ql * 8;
        *(float4*)op = o0;
        *(float4*)(op + 4) = o1;
    }
}

extern "C" void kernel_launch(void* const* d_in, const int* in_sizes, int n_in,
                              void* d_out, int out_size, void* d_ws, size_t ws_size,
                              hipStream_t stream) {
    const int* ei     = (const int*)d_in[0];    // [2, E] int32
    const float* xsrc = (const float*)d_in[1];  // [NSRC, 128]
    const float* xtgt = (const float*)d_in[2];  // [NTGT, 128]
    const float* W    = (const float*)d_in[3];  // [128, 128]
    float* out = (float*)d_out;                 // [NTOT, 128]

    const int* row = ei;
    const int* col = ei + NEDGE;

    char* ws = (char*)d_ws;
    unsigned short* h  = (unsigned short*)ws;  ws += (size_t)NTOT * DIM * 2;   // 25.6 MB
    unsigned short* Wt = (unsigned short*)ws;  ws += DIM * DIM * 2;            // 32 KB
    unsigned* part = (unsigned*)ws;            ws += (size_t)NBUCK * BCAP * 4; // 4.8 MB
    unsigned short* csr = (unsigned short*)ws; ws += (size_t)NBUCK * BCAP * 2; // 2.4 MB
    int* bcnt   = (int*)ws;                    ws += NBUCK * 4;
    int* tstart = (int*)ws;                    ws += NTGT * 4;
    int* tcnt   = (int*)ws;                    ws += NTGT * 4;

    k_prep<<<(DIM * DIM + 255) / 256, 256, 0, stream>>>(W, Wt, bcnt);
    k_part2<<<PBLK, 1024, 0, stream>>>(row, col, bcnt, part);
    k_bucket<<<NBUCK, 1024, 0, stream>>>(bcnt, part, csr, tstart, tcnt);
    k_gemm<<<GEMM_GRID, 256, 0, stream>>>(xsrc, xtgt, Wt, h, out);
    k_agg<<<(NTGT + 3) / 4, 256, 0, stream>>>(tstart, tcnt, csr, h, out);
}

// Round 11
// 164.181 us; speedup vs baseline: 1.1081x; 1.0638x over previous
//
#include <hip/hip_runtime.h>
#include <hip/hip_bf16.h>
#include <math.h>

#define NSRC 50000
#define NTGT 50000
#define NTOT 100000
#define NEDGE 800000
#define DIM 128
#define WPAD 136        // Bs LDS row pitch (ushorts): 2-way bank alias = free
#define GEMM_GRID 1563  // ceil(100000 / 64) -- 1 chunk/block, small tail

#define NBUCK 196       // coarse buckets of 256 targets (49999>>8 = 195)
#define PBLK 98         // partition blocks
#define EPB 8192        // edges per partition block (98*8192 >= 800000)
#define EPT 8           // edges per thread in k_part2 (1024 thr * 8 = 8192)
#define BCAP 6144       // max edges per bucket (mean 4096, +32 sigma)

typedef __attribute__((ext_vector_type(8))) short short8;
typedef __attribute__((ext_vector_type(4))) float float4v;

union U8 { short8 s; uint4 u; };

__device__ __forceinline__ unsigned short f2bf(float f) {
    unsigned u = __float_as_uint(f);
    unsigned r = (u + 0x7FFFu + ((u >> 16) & 1u)) >> 16;  // RNE
    return (unsigned short)r;
}
__device__ __forceinline__ float bf2f(unsigned us) {
    return __uint_as_float(us << 16);
}
// packed RNE f32x2 -> bf16x2 (v_cvt_pk_bf16_f32)
__device__ __forceinline__ unsigned pkbf(float lo, float hi) {
    __hip_bfloat162 b = __float22bfloat162_rn(make_float2(lo, hi));
    return *(unsigned*)&b;
}

// ---------------- prep: W -> Wt (bf16, transposed) + zero bcnt ------------
__global__ void k_prep(const float* __restrict__ W, unsigned short* __restrict__ Wt,
                       int* __restrict__ bcnt) {
    int i = blockIdx.x * blockDim.x + threadIdx.x;
    if (i < NBUCK) bcnt[i] = 0;
    if (i < DIM * DIM) {
        int k = i >> 7, n = i & 127;
        Wt[n * DIM + k] = f2bf(W[i]);
    }
}

// ---------------- fused count + run-reserve + partition (single read) -----
// packed entry: row (16 bits) | c_local (bits 16..23)
__global__ __launch_bounds__(1024) void k_part2(const int* __restrict__ row,
                                                const int* __restrict__ col,
                                                int* __restrict__ bcnt,
                                                unsigned* __restrict__ part) {
    __shared__ int hist[NBUCK], runbase[NBUCK], cur[NBUCK];
    int tid = threadIdx.x;
    if (tid < NBUCK) hist[tid] = 0;
    __syncthreads();

    int e0 = blockIdx.x * EPB + tid * EPT;
    bool valid = (e0 + EPT <= NEDGE);  // NEDGE%8==0 -> all-or-nothing
    int c[EPT], r[EPT];
    if (valid) {
        *(int4*)&c[0] = *(const int4*)(col + e0);
        *(int4*)&c[4] = *(const int4*)(col + e0 + 4);
        *(int4*)&r[0] = *(const int4*)(row + e0);
        *(int4*)&r[4] = *(const int4*)(row + e0 + 4);
#pragma unroll
        for (int i = 0; i < EPT; ++i) atomicAdd(&hist[c[i] >> 8], 1);
    }
    __syncthreads();
    if (tid < NBUCK) {
        runbase[tid] = atomicAdd(&bcnt[tid], hist[tid]);  // reserve run
        cur[tid] = 0;
    }
    __syncthreads();
    if (valid) {
#pragma unroll
        for (int i = 0; i < EPT; ++i) {
            int q = c[i] >> 8;
            int pos = runbase[q] + atomicAdd(&cur[q], 1);
            part[q * BCAP + pos] = (unsigned)r[i] | ((unsigned)(c[i] & 255) << 16);
        }
    }
}

// ---------------- per-bucket local sort -> csr (ushort) + tstart/tcnt -----
__global__ __launch_bounds__(1024) void k_bucket(const int* __restrict__ bcnt,
                                                 const unsigned* __restrict__ part,
                                                 unsigned short* __restrict__ csr,
                                                 int* __restrict__ tstart,
                                                 int* __restrict__ tcnt) {
    __shared__ unsigned ebuf[BCAP];
    __shared__ unsigned short srt[BCAP];
    __shared__ int hist[256], bufA[256], bufB[256], cur[256];

    int q = blockIdx.x, tid = threadIdx.x;
    int n = bcnt[q];
    int base = q * BCAP;

    if (tid < 256) hist[tid] = 0;
    __syncthreads();
    for (int i = tid; i < n; i += 1024) {
        unsigned p = part[base + i];
        ebuf[i] = p;
        atomicAdd(&hist[p >> 16], 1);
    }
    __syncthreads();

    // exclusive scan of hist[256] (first 256 threads, double-buffered)
    if (tid < 256) bufA[tid] = hist[tid];
    int* src = bufA; int* dst = bufB;
    for (int d = 1; d < 256; d <<= 1) {
        __syncthreads();
        if (tid < 256) dst[tid] = src[tid] + ((tid >= d) ? src[tid - d] : 0);
        int* t = src; src = dst; dst = t;
    }
    __syncthreads();
    if (tid < 256) {
        int excl = src[tid] - hist[tid];
        cur[tid] = excl;
        int c = q * 256 + tid;
        if (c < NTGT) {
            tstart[c] = base + excl;
            tcnt[c] = hist[tid];
        }
    }
    __syncthreads();

    for (int i = tid; i < n; i += 1024) {
        unsigned p = ebuf[i];
        int pos = atomicAdd(&cur[p >> 16], 1);
        srt[pos] = (unsigned short)(p & 0xffffu);
    }
    __syncthreads();
    // coalesced writeout, 2 ushorts per store (base is 4B-aligned: BCAP even)
    int m = (n + 1) >> 1;
    unsigned* dst32 = (unsigned*)(csr + base);
    for (int i = tid; i < m; i += 1024) dst32[i] = ((unsigned*)srt)[i];
}

// ---------------- h = x @ W via bf16 MFMA (operand-swapped, no Hs) --------
// 64 rows per block (1 chunk), grid 1563 -> ~6 rounds/CU, small tail.
// mfma(A=W^T frag, B=x frag): lane owns 4 consecutive features of one node
// -> direct uint2 global stores, no LDS epilogue staging.
__global__ __launch_bounds__(256) void k_gemm(const float* __restrict__ xsrc,
                                              const float* __restrict__ xtgt,
                                              const unsigned short* __restrict__ Wt,
                                              unsigned short* __restrict__ h,
                                              float* __restrict__ out) {
    __shared__ unsigned short Bs[128 * WPAD];  // 34 KB -> 4 blocks/CU

    const int tid = threadIdx.x;
    for (int idx = tid; idx < 2048; idx += 256) {
        int n = idx >> 4, c8 = idx & 15;
        *(uint4*)&Bs[n * WPAD + c8 * 8] = *(const uint4*)(Wt + n * DIM + c8 * 8);
    }

    const int wave = tid >> 6, lane = tid & 63;
    const int nl = lane & 15, quad = lane >> 4;

    // prefetch x fragments (issued before the Bs barrier)
    int node = blockIdx.x * 64 + wave * 16 + nl;
    int mc = (node < NTOT) ? node : (NTOT - 1);  // clamp tail loads
    const float* xrow = (mc < NSRC) ? (xsrc + (size_t)mc * DIM)
                                    : (xtgt + (size_t)(mc - NSRC) * DIM);
    float4 a[8];
#pragma unroll
    for (int s = 0; s < 4; ++s) {
        a[2 * s]     = *(const float4*)(xrow + s * 32 + quad * 8);
        a[2 * s + 1] = *(const float4*)(xrow + s * 32 + quad * 8 + 4);
    }
    __syncthreads();  // Bs ready

    float4v acc[8];
#pragma unroll
    for (int t = 0; t < 8; ++t) acc[t] = (float4v){0.f, 0.f, 0.f, 0.f};

#pragma unroll
    for (int s = 0; s < 4; ++s) {
        U8 af;
        af.u.x = pkbf(a[2 * s].x, a[2 * s].y);
        af.u.y = pkbf(a[2 * s].z, a[2 * s].w);
        af.u.z = pkbf(a[2 * s + 1].x, a[2 * s + 1].y);
        af.u.w = pkbf(a[2 * s + 1].z, a[2 * s + 1].w);
#pragma unroll
        for (int t = 0; t < 8; ++t) {
            short8 bf = *(const short8*)&Bs[(t * 16 + nl) * WPAD + s * 32 + quad * 8];
            // A = W^T tile (features as M), B = x tile (nodes as N)
            acc[t] = __builtin_amdgcn_mfma_f32_16x16x32_bf16(bf, af.s, acc[t], 0, 0, 0);
        }
    }

    if (node < NTOT) {
        // lane owns node `node`, features t*16 + quad*4 .. +3
        unsigned short* hp = h + (size_t)node * DIM + quad * 4;
        float* op = out + (size_t)node * DIM + quad * 4;
        bool isrc = (node < NSRC);
#pragma unroll
        for (int t = 0; t < 8; ++t) {
            uint2 p;
            p.x = pkbf(acc[t][0], acc[t][1]);
            p.y = pkbf(acc[t][2], acc[t][3]);
            *(uint2*)(hp + t * 16) = p;
            if (isrc) {  // source nodes: deg=1 -> out = relu(h), fp32 acc
                float4 o;
                o.x = fmaxf(acc[t][0], 0.f);
                o.y = fmaxf(acc[t][1], 0.f);
                o.z = fmaxf(acc[t][2], 0.f);
                o.w = fmaxf(acc[t][3], 0.f);
                *(float4*)(op + t * 16) = o;
            }
        }
    }
}

// ---------------- per-target gather-reduce (bf16 h, 4 edges/iter) ---------
// one wave per target; quarter-wave (16 lanes) per edge, uint4 (8 bf16)/lane
__global__ __launch_bounds__(256) void k_agg(const int* __restrict__ tstart,
                                             const int* __restrict__ tcnt,
                                             const unsigned short* __restrict__ csr,
                                             const unsigned short* __restrict__ h,
                                             float* __restrict__ out) {
    int w = threadIdx.x >> 6;
    int lane = threadIdx.x & 63;
    int c = blockIdx.x * 4 + w;
    if (c >= NTGT) return;

    int n = tcnt[c];
    int s0 = tstart[c];
    int q = lane >> 4;      // quarter: which edge of the group of 4
    int ql = lane & 15;     // covers cols 8*ql .. 8*ql+7

    float acc[8];
#pragma unroll
    for (int i = 0; i < 8; ++i) acc[i] = 0.f;

    int j = 0;
    while (j < n) {
        int nb = (n - j < 64) ? (n - j) : 64;
        int v = (lane < nb) ? (int)csr[s0 + j + lane] : 0;
        int n4 = nb & ~3;
        int kk = 0;
#pragma unroll 4
        for (; kk < n4; kk += 4) {
            int r = __shfl(v, kk + q, 64);
            uint4 d = *(const uint4*)(h + (size_t)r * DIM + ql * 8);
            acc[0] += bf2f(d.x & 0xffff); acc[1] += bf2f(d.x >> 16);
            acc[2] += bf2f(d.y & 0xffff); acc[3] += bf2f(d.y >> 16);
            acc[4] += bf2f(d.z & 0xffff); acc[5] += bf2f(d.z >> 16);
            acc[6] += bf2f(d.w & 0xffff); acc[7] += bf2f(d.w >> 16);
        }
        int rem = nb - kk;  // 0..3, wave-uniform
        if (rem) {
            // shfl executed by ALL lanes (divergent-source bpermute is UB)
            int qq = (q < rem) ? q : 0;
            int r = __shfl(v, kk + qq, 64);
            if (q < rem) {
                uint4 d = *(const uint4*)(h + (size_t)r * DIM + ql * 8);
                acc[0] += bf2f(d.x & 0xffff); acc[1] += bf2f(d.x >> 16);
                acc[2] += bf2f(d.y & 0xffff); acc[3] += bf2f(d.y >> 16);
                acc[4] += bf2f(d.z & 0xffff); acc[5] += bf2f(d.z >> 16);
                acc[6] += bf2f(d.w & 0xffff); acc[7] += bf2f(d.w >> 16);
            }
        }
        j += nb;
    }

    // combine quarters: butterfly over lane bits 4,5
#pragma unroll
    for (int i = 0; i < 8; ++i) {
        acc[i] += __shfl_xor(acc[i], 16, 64);
        acc[i] += __shfl_xor(acc[i], 32, 64);
    }

    if (q == 0) {
        float di = rsqrtf(1.0f + (float)n);
        float dd = di * di;
        uint4 dh = *(const uint4*)(h + (size_t)(NSRC + c) * DIM + ql * 8);
        float4 o0, o1;
        o0.x = fmaxf(di * acc[0] + dd * bf2f(dh.x & 0xffff), 0.f);
        o0.y = fmaxf(di * acc[1] + dd * bf2f(dh.x >> 16), 0.f);
        o0.z = fmaxf(di * acc[2] + dd * bf2f(dh.y & 0xffff), 0.f);
        o0.w = fmaxf(di * acc[3] + dd * bf2f(dh.y >> 16), 0.f);
        o1.x = fmaxf(di * acc[4] + dd * bf2f(dh.z & 0xffff), 0.f);
        o1.y = fmaxf(di * acc[5] + dd * bf2f(dh.z >> 16), 0.f);
        o1.z = fmaxf(di * acc[6] + dd * bf2f(dh.w & 0xffff), 0.f);
        o1.w = fmaxf(di * acc[7] + dd * bf2f(dh.w >> 16), 0.f);
        float* op = out + (size_t)(NSRC + c) * DIM + ql * 8;
        *(float4*)op = o0;
        *(float4*)(op + 4) = o1;
    }
}

extern "C" void kernel_launch(void* const* d_in, const int* in_sizes, int n_in,
                              void* d_out, int out_size, void* d_ws, size_t ws_size,
                              hipStream_t stream) {
    const int* ei     = (const int*)d_in[0];    // [2, E] int32
    const float* xsrc = (const float*)d_in[1];  // [NSRC, 128]
    const float* xtgt = (const float*)d_in[2];  // [NTGT, 128]
    const float* W    = (const float*)d_in[3];  // [128, 128]
    float* out = (float*)d_out;                 // [NTOT, 128]

    const int* row = ei;
    const int* col = ei + NEDGE;

    char* ws = (char*)d_ws;
    unsigned short* h  = (unsigned short*)ws;  ws += (size_t)NTOT * DIM * 2;   // 25.6 MB
    unsigned short* Wt = (unsigned short*)ws;  ws += DIM * DIM * 2;            // 32 KB
    unsigned* part = (unsigned*)ws;            ws += (size_t)NBUCK * BCAP * 4; // 4.8 MB
    unsigned short* csr = (unsigned short*)ws; ws += (size_t)NBUCK * BCAP * 2; // 2.4 MB
    int* bcnt   = (int*)ws;                    ws += NBUCK * 4;
    int* tstart = (int*)ws;                    ws += NTGT * 4;
    int* tcnt   = (int*)ws;                    ws += NTGT * 4;

    k_prep<<<(DIM * DIM + 255) / 256, 256, 0, stream>>>(W, Wt, bcnt);
    k_part2<<<PBLK, 1024, 0, stream>>>(row, col, bcnt, part);
    k_bucket<<<NBUCK, 1024, 0, stream>>>(bcnt, part, csr, tstart, tcnt);
    k_gemm<<<GEMM_GRID, 256, 0, stream>>>(xsrc, xtgt, Wt, h, out);
    k_agg<<<(NTGT + 3) / 4, 256, 0, stream>>>(tstart, tcnt, csr, h, out);
}